// Round 8
// baseline (438.633 us; speedup 1.0000x reference)
//
#include <hip/hip_runtime.h>
#include <math.h>

#define EMBED 64

__device__ __forceinline__ float dot4(float4 a, float4 b) {
    return fmaf(a.x, b.x, fmaf(a.y, b.y, fmaf(a.z, b.z, a.w * b.w)));
}

// reduce across the 16 lanes of an edge-subgroup (lane bits 0..3)
__device__ __forceinline__ float red16(float d) {
    d += __shfl_xor(d, 1);
    d += __shfl_xor(d, 2);
    d += __shfl_xor(d, 4);
    d += __shfl_xor(d, 8);
    return d;
}

// ---------------- K1: CSR rowptr build + edge-parallel logits (independent phases) ----------------
__global__ void __launch_bounds__(256, 8) rowptr_logits_kernel(
        const float* __restrict__ ha, const float* __restrict__ ta,
        const int* __restrict__ row, const int* __restrict__ col,
        int* __restrict__ rp, float* __restrict__ logits,
        int E, int N, int totalThreads, int totalWaves) {
    int tid = blockIdx.x * blockDim.x + threadIdx.x;

    // phase A: rowptr boundary scatter (thread per edge, grid-stride)
    for (int i = tid; i < E; i += totalThreads) {
        if (i == 0) {
            int r0 = row[0];
            for (int r = 0; r <= r0; ++r) rp[r] = 0;
        } else {
            int a = row[i - 1], b = row[i];
            for (int r = a + 1; r <= b; ++r) rp[r] = i;
        }
        if (i == E - 1) {
            int rl = row[E - 1];
            for (int r = rl + 1; r <= N; ++r) rp[r] = E;
        }
    }

    // phase B: logits, 16 edges/wave/iter = 8 row-gathers in flight
    int wid = tid >> 6;
    int lane = threadIdx.x & 63;
    int eg = lane >> 4, q = lane & 15;
    const float4* ha4 = (const float4*)ha;
    const float4* ta4 = (const float4*)ta;

    for (int base = wid * 16; base < E; base += totalWaves * 16) {
        int j0 = base + eg, j1 = base + 4 + eg, j2 = base + 8 + eg, j3 = base + 12 + eg;
        int i0 = min(j0, E - 1), i1 = min(j1, E - 1);
        int i2 = min(j2, E - 1), i3 = min(j3, E - 1);
        int r0 = row[i0], r1 = row[i1], r2 = row[i2], r3 = row[i3];
        int c0 = col[i0], c1 = col[i1], c2 = col[i2], c3 = col[i3];
        float4 t0 = ta4[(size_t)c0 * 16 + q];
        float4 t1 = ta4[(size_t)c1 * 16 + q];
        float4 t2 = ta4[(size_t)c2 * 16 + q];
        float4 t3 = ta4[(size_t)c3 * 16 + q];
        float4 a0 = ha4[(size_t)r0 * 16 + q];
        float4 a1 = ha4[(size_t)r1 * 16 + q];
        float4 a2 = ha4[(size_t)r2 * 16 + q];
        float4 a3 = ha4[(size_t)r3 * 16 + q];
        float d0 = red16(dot4(a0, t0));
        float d1 = red16(dot4(a1, t1));
        float d2 = red16(dot4(a2, t2));
        float d3 = red16(dot4(a3, t3));
        if (q == 0) {
            if (j0 < E) logits[j0] = d0;
            if (j1 < E) logits[j1] = d1;
            if (j2 < E) logits[j2] = d2;
            if (j3 < E) logits[j3] = d3;
        }
    }
}

// ---------------- K2: out[0]=h0 copy + per-node softmax (grid-stride both) ----------------
__global__ void __launch_bounds__(256) copy_softmax_kernel(
        const float* __restrict__ h0, float* __restrict__ out0, int n4,
        const int* __restrict__ rp, float* __restrict__ lw, int N,
        int totalThreads, int totalWaves) {
    int tid = blockIdx.x * blockDim.x + threadIdx.x;
    // phase A: float4 copy
    for (int i = tid; i < n4; i += totalThreads)
        ((float4*)out0)[i] = ((const float4*)h0)[i];

    // phase B: wave-per-node softmax, in-place logits -> weights
    int wid = tid >> 6;
    int lane = threadIdx.x & 63;
    for (int n = wid; n < N; n += totalWaves) {
        int s = rp[n], t = rp[n + 1];
        int deg = t - s;
        if (deg <= 0) continue;
        if (deg <= 64) {
            float v = (lane < deg) ? lw[s + lane] : -1e30f;
            float m = v;
            #pragma unroll
            for (int off = 32; off > 0; off >>= 1) m = fmaxf(m, __shfl_xor(m, off));
            float e = (lane < deg) ? __expf(v - m) : 0.f;
            float sum = e;
            #pragma unroll
            for (int off = 32; off > 0; off >>= 1) sum += __shfl_xor(sum, off);
            float inv = 1.f / fmaxf(sum, 1e-12f);
            if (lane < deg) lw[s + lane] = e * inv;
        } else {
            float m = -1e30f;
            for (int e = s + lane; e < t; e += 64) m = fmaxf(m, lw[e]);
            #pragma unroll
            for (int off = 32; off > 0; off >>= 1) m = fmaxf(m, __shfl_xor(m, off));
            float sum = 0.f;
            for (int e = s + lane; e < t; e += 64) sum += __expf(lw[e] - m);
            #pragma unroll
            for (int off = 32; off > 0; off >>= 1) sum += __shfl_xor(sum, off);
            float inv = 1.f / fmaxf(sum, 1e-12f);
            for (int e = s + lane; e < t; e += 64) lw[e] = __expf(lw[e] - m) * inv;
        }
    }
}

// ---------------- K3/K4: fused prop layer: spmm gather + dense + norm ----------------
// W lives in LDS (block-shared, row pitch 68 floats -> per-lane ds_read_b128 is
// bank-balanced: lane*68 mod 32 spreads lanes across all 32 banks, 8 hits each).
// Frees 64 VGPRs/lane -> ~8 waves/SIMD resident; grid 2048 = 8 blocks/CU
// (LDS 18.5 KB/block x 8 = 148 KB < 160 KB). More resident waves -> more
// 1KB gathers in flight -> approach the ~3.3 TB/s gather wall.
__global__ void __launch_bounds__(256, 4) prop_layer_kernel(
        const float* __restrict__ h_in,
        const float* __restrict__ W, const float* __restrict__ b,
        const int* __restrict__ col, const float* __restrict__ ew,
        const int* __restrict__ rp,
        float* __restrict__ out, int N, int totalWaves) {
    __shared__ float Wl[64 * 68];           // padded pitch 68 -> bank-balanced
    __shared__ float4 rbuf[4][17];
    int wid = (blockIdx.x * blockDim.x + threadIdx.x) >> 6;
    int lane = threadIdx.x & 63;
    int ws = threadIdx.x >> 6;
    int eg = lane >> 4, q = lane & 15;
    const float4* h4 = (const float4*)h_in;
    const float4* W4 = (const float4*)W;

    // stage W into LDS once (256 threads x 4 float4)
    for (int idx = threadIdx.x; idx < 1024; idx += 256) {
        int r = idx >> 4, c4 = (idx & 15) << 2;
        float4 v = W4[idx];
        *(float4*)&Wl[r * 68 + c4] = v;
    }
    float bias = b[lane];
    __syncthreads();
    const float* Wrow = &Wl[lane * 68];

    for (int n = wid; n < N; n += totalWaves) {
        int s = rp[n], t = rp[n + 1];
        float4 self = h4[(size_t)n * 16 + q];
        float4 a0 = make_float4(0.f, 0.f, 0.f, 0.f);
        float4 a1 = make_float4(0.f, 0.f, 0.f, 0.f);
        int e0 = s;
        for (; e0 + 16 <= t; e0 += 16) {               // unclamped main step
            int i0 = e0 + eg, i1 = e0 + 4 + eg, i2 = e0 + 8 + eg, i3 = e0 + 12 + eg;
            int c0 = col[i0], c1 = col[i1], c2 = col[i2], c3 = col[i3];
            float w0 = ew[i0], w1 = ew[i1], w2 = ew[i2], w3 = ew[i3];
            float4 v0 = h4[(size_t)c0 * 16 + q];
            float4 v1 = h4[(size_t)c1 * 16 + q];
            float4 v2 = h4[(size_t)c2 * 16 + q];
            float4 v3 = h4[(size_t)c3 * 16 + q];
            a0.x = fmaf(w0, v0.x, a0.x); a0.y = fmaf(w0, v0.y, a0.y);
            a0.z = fmaf(w0, v0.z, a0.z); a0.w = fmaf(w0, v0.w, a0.w);
            a1.x = fmaf(w1, v1.x, a1.x); a1.y = fmaf(w1, v1.y, a1.y);
            a1.z = fmaf(w1, v1.z, a1.z); a1.w = fmaf(w1, v1.w, a1.w);
            a0.x = fmaf(w2, v2.x, a0.x); a0.y = fmaf(w2, v2.y, a0.y);
            a0.z = fmaf(w2, v2.z, a0.z); a0.w = fmaf(w2, v2.w, a0.w);
            a1.x = fmaf(w3, v3.x, a1.x); a1.y = fmaf(w3, v3.y, a1.y);
            a1.z = fmaf(w3, v3.z, a1.z); a1.w = fmaf(w3, v3.w, a1.w);
        }
        if (e0 < t) {                                  // one clamped tail step
            int j0 = e0 + eg, j1 = e0 + 4 + eg, j2 = e0 + 8 + eg, j3 = e0 + 12 + eg;
            int i0 = min(j0, t - 1), i1 = min(j1, t - 1);
            int i2 = min(j2, t - 1), i3 = min(j3, t - 1);
            int c0 = col[i0], c1 = col[i1], c2 = col[i2], c3 = col[i3];
            float w0 = (j0 < t) ? ew[i0] : 0.f;
            float w1 = (j1 < t) ? ew[i1] : 0.f;
            float w2 = (j2 < t) ? ew[i2] : 0.f;
            float w3 = (j3 < t) ? ew[i3] : 0.f;
            float4 v0 = h4[(size_t)c0 * 16 + q];
            float4 v1 = h4[(size_t)c1 * 16 + q];
            float4 v2 = h4[(size_t)c2 * 16 + q];
            float4 v3 = h4[(size_t)c3 * 16 + q];
            a0.x = fmaf(w0, v0.x, a0.x); a0.y = fmaf(w0, v0.y, a0.y);
            a0.z = fmaf(w0, v0.z, a0.z); a0.w = fmaf(w0, v0.w, a0.w);
            a1.x = fmaf(w1, v1.x, a1.x); a1.y = fmaf(w1, v1.y, a1.y);
            a1.z = fmaf(w1, v1.z, a1.z); a1.w = fmaf(w1, v1.w, a1.w);
            a0.x = fmaf(w2, v2.x, a0.x); a0.y = fmaf(w2, v2.y, a0.y);
            a0.z = fmaf(w2, v2.z, a0.z); a0.w = fmaf(w2, v2.w, a0.w);
            a1.x = fmaf(w3, v3.x, a1.x); a1.y = fmaf(w3, v3.y, a1.y);
            a1.z = fmaf(w3, v3.z, a1.z); a1.w = fmaf(w3, v3.w, a1.w);
        }
        a0.x += a1.x; a0.y += a1.y; a0.z += a1.z; a0.w += a1.w;
        // xor-butterfly over lane bits 4,5: all lanes end with the edge total
        a0.x += __shfl_xor(a0.x, 16); a0.y += __shfl_xor(a0.y, 16);
        a0.z += __shfl_xor(a0.z, 16); a0.w += __shfl_xor(a0.w, 16);
        a0.x += __shfl_xor(a0.x, 32); a0.y += __shfl_xor(a0.y, 32);
        a0.z += __shfl_xor(a0.z, 32); a0.w += __shfl_xor(a0.w, 32);

        // stage add-row to LDS (lanes 0-15 cover the 64 floats)
        if (eg == 0) {
            float4 r;
            r.x = self.x + a0.x; r.y = self.y + a0.y;
            r.z = self.z + a0.z; r.w = self.w + a0.w;
            rbuf[ws][q] = r;
        }
        asm volatile("s_waitcnt lgkmcnt(0)" ::: "memory");  // wave-synchronous

        // dense: x[lane] = relu(add . W[lane] + b[lane]), then L2-normalize.
        // add from uniform-address broadcasts; W row from bank-balanced LDS.
        float x0 = bias, x1 = 0.f, x2 = 0.f, x3 = 0.f;
        #pragma unroll
        for (int j = 0; j < 4; ++j) {
            float4 b0 = rbuf[ws][4 * j + 0];
            float4 b1 = rbuf[ws][4 * j + 1];
            float4 b2 = rbuf[ws][4 * j + 2];
            float4 b3 = rbuf[ws][4 * j + 3];
            float4 w0 = *(const float4*)&Wrow[(4 * j + 0) * 4];
            float4 w1 = *(const float4*)&Wrow[(4 * j + 1) * 4];
            float4 w2 = *(const float4*)&Wrow[(4 * j + 2) * 4];
            float4 w3 = *(const float4*)&Wrow[(4 * j + 3) * 4];
            x0 = fmaf(b0.x, w0.x, x0); x0 = fmaf(b0.y, w0.y, x0);
            x0 = fmaf(b0.z, w0.z, x0); x0 = fmaf(b0.w, w0.w, x0);
            x1 = fmaf(b1.x, w1.x, x1); x1 = fmaf(b1.y, w1.y, x1);
            x1 = fmaf(b1.z, w1.z, x1); x1 = fmaf(b1.w, w1.w, x1);
            x2 = fmaf(b2.x, w2.x, x2); x2 = fmaf(b2.y, w2.y, x2);
            x2 = fmaf(b2.z, w2.z, x2); x2 = fmaf(b2.w, w2.w, x2);
            x3 = fmaf(b3.x, w3.x, x3); x3 = fmaf(b3.y, w3.y, x3);
            x3 = fmaf(b3.z, w3.z, x3); x3 = fmaf(b3.w, w3.w, x3);
        }
        float x = fmaxf((x0 + x1) + (x2 + x3), 0.f);

        float ss = x * x;
        #pragma unroll
        for (int off = 32; off > 0; off >>= 1) ss += __shfl_xor(ss, off);
        float scale = 1.f / fmaxf(sqrtf(ss), 1e-12f);
        out[(size_t)n * EMBED + lane] = x * scale;
    }
}

extern "C" void kernel_launch(void* const* d_in, const int* in_sizes, int n_in,
                              void* d_out, int out_size, void* d_ws, size_t ws_size,
                              hipStream_t stream) {
    const float* h0   = (const float*)d_in[0];
    const float* ha   = (const float*)d_in[1];
    const float* ta   = (const float*)d_in[2];
    const float* w1   = (const float*)d_in[3];
    const float* b1   = (const float*)d_in[4];
    const float* w2   = (const float*)d_in[5];
    const float* b2   = (const float*)d_in[6];
    const int*   erow = (const int*)d_in[7];
    const int*   ecol = (const int*)d_in[8];

    const int N = in_sizes[0] / EMBED;
    const int E = in_sizes[7];
    float* out = (float*)d_out;

    // workspace: row_ptr[N+1] ints, then edge weights[E] floats
    int*   rp = (int*)d_ws;
    size_t rp_bytes = ((size_t)(N + 1) * sizeof(int) + 255) & ~(size_t)255;
    float* ew = (float*)((char*)d_ws + rp_bytes);

    // K1: rowptr + logits (independent phases, one launch)
    rowptr_logits_kernel<<<2048, 256, 0, stream>>>(
        ha, ta, erow, ecol, rp, ew, E, N, 2048 * 256, 2048 * 4);

    // K2: out[0] = h0 copy + per-node softmax
    copy_softmax_kernel<<<2048, 256, 0, stream>>>(
        h0, out, N * EMBED / 4, rp, ew, N, 2048 * 256, 2048 * 4);

    // K3/K4: fused prop layers (grid 2048 = 8 blocks/CU with 18.5 KB LDS)
    float* out1 = out + (size_t)N * EMBED;
    float* out2 = out + 2 * (size_t)N * EMBED;
    prop_layer_kernel<<<2048, 256, 0, stream>>>(h0,   w1, b1, ecol, ew, rp, out1, N, 2048 * 4);
    prop_layer_kernel<<<2048, 256, 0, stream>>>(out1, w2, b2, ecol, ew, rp, out2, N, 2048 * 4);
}

// Round 9
// 429.997 us; speedup vs baseline: 1.0201x; 1.0201x over previous
//
#include <hip/hip_runtime.h>
#include <math.h>

#define EMBED 64

__device__ __forceinline__ float dot4(float4 a, float4 b) {
    return fmaf(a.x, b.x, fmaf(a.y, b.y, fmaf(a.z, b.z, a.w * b.w)));
}

// reduce across the 16 lanes of an edge-subgroup (lane bits 0..3)
__device__ __forceinline__ float red16(float d) {
    d += __shfl_xor(d, 1);
    d += __shfl_xor(d, 2);
    d += __shfl_xor(d, 4);
    d += __shfl_xor(d, 8);
    return d;
}

// ---------------- K1: CSR rowptr build + edge-parallel logits (independent phases) ----------------
__global__ void __launch_bounds__(256, 8) rowptr_logits_kernel(
        const float* __restrict__ ha, const float* __restrict__ ta,
        const int* __restrict__ row, const int* __restrict__ col,
        int* __restrict__ rp, float* __restrict__ logits,
        int E, int N, int totalThreads, int totalWaves) {
    int tid = blockIdx.x * blockDim.x + threadIdx.x;

    // phase A: rowptr boundary scatter (thread per edge, grid-stride)
    for (int i = tid; i < E; i += totalThreads) {
        if (i == 0) {
            int r0 = row[0];
            for (int r = 0; r <= r0; ++r) rp[r] = 0;
        } else {
            int a = row[i - 1], b = row[i];
            for (int r = a + 1; r <= b; ++r) rp[r] = i;
        }
        if (i == E - 1) {
            int rl = row[E - 1];
            for (int r = rl + 1; r <= N; ++r) rp[r] = E;
        }
    }

    // phase B: logits, 16 edges/wave/iter = 8 row-gathers in flight
    int wid = tid >> 6;
    int lane = threadIdx.x & 63;
    int eg = lane >> 4, q = lane & 15;
    const float4* ha4 = (const float4*)ha;
    const float4* ta4 = (const float4*)ta;

    for (int base = wid * 16; base < E; base += totalWaves * 16) {
        int j0 = base + eg, j1 = base + 4 + eg, j2 = base + 8 + eg, j3 = base + 12 + eg;
        int i0 = min(j0, E - 1), i1 = min(j1, E - 1);
        int i2 = min(j2, E - 1), i3 = min(j3, E - 1);
        int r0 = row[i0], r1 = row[i1], r2 = row[i2], r3 = row[i3];
        int c0 = col[i0], c1 = col[i1], c2 = col[i2], c3 = col[i3];
        float4 t0 = ta4[(size_t)c0 * 16 + q];
        float4 t1 = ta4[(size_t)c1 * 16 + q];
        float4 t2 = ta4[(size_t)c2 * 16 + q];
        float4 t3 = ta4[(size_t)c3 * 16 + q];
        float4 a0 = ha4[(size_t)r0 * 16 + q];
        float4 a1 = ha4[(size_t)r1 * 16 + q];
        float4 a2 = ha4[(size_t)r2 * 16 + q];
        float4 a3 = ha4[(size_t)r3 * 16 + q];
        float d0 = red16(dot4(a0, t0));
        float d1 = red16(dot4(a1, t1));
        float d2 = red16(dot4(a2, t2));
        float d3 = red16(dot4(a3, t3));
        if (q == 0) {
            if (j0 < E) logits[j0] = d0;
            if (j1 < E) logits[j1] = d1;
            if (j2 < E) logits[j2] = d2;
            if (j3 < E) logits[j3] = d3;
        }
    }
}

// ---------------- K2: out[0]=h0 copy + per-node softmax (grid-stride both) ----------------
__global__ void __launch_bounds__(256) copy_softmax_kernel(
        const float* __restrict__ h0, float* __restrict__ out0, int n4,
        const int* __restrict__ rp, float* __restrict__ lw, int N,
        int totalThreads, int totalWaves) {
    int tid = blockIdx.x * blockDim.x + threadIdx.x;
    // phase A: float4 copy
    for (int i = tid; i < n4; i += totalThreads)
        ((float4*)out0)[i] = ((const float4*)h0)[i];

    // phase B: wave-per-node softmax, in-place logits -> weights
    int wid = tid >> 6;
    int lane = threadIdx.x & 63;
    for (int n = wid; n < N; n += totalWaves) {
        int s = rp[n], t = rp[n + 1];
        int deg = t - s;
        if (deg <= 0) continue;
        if (deg <= 64) {
            float v = (lane < deg) ? lw[s + lane] : -1e30f;
            float m = v;
            #pragma unroll
            for (int off = 32; off > 0; off >>= 1) m = fmaxf(m, __shfl_xor(m, off));
            float e = (lane < deg) ? __expf(v - m) : 0.f;
            float sum = e;
            #pragma unroll
            for (int off = 32; off > 0; off >>= 1) sum += __shfl_xor(sum, off);
            float inv = 1.f / fmaxf(sum, 1e-12f);
            if (lane < deg) lw[s + lane] = e * inv;
        } else {
            float m = -1e30f;
            for (int e = s + lane; e < t; e += 64) m = fmaxf(m, lw[e]);
            #pragma unroll
            for (int off = 32; off > 0; off >>= 1) m = fmaxf(m, __shfl_xor(m, off));
            float sum = 0.f;
            for (int e = s + lane; e < t; e += 64) sum += __expf(lw[e] - m);
            #pragma unroll
            for (int off = 32; off > 0; off >>= 1) sum += __shfl_xor(sum, off);
            float inv = 1.f / fmaxf(sum, 1e-12f);
            for (int e = s + lane; e < t; e += 64) lw[e] = __expf(lw[e] - m) * inv;
        }
    }
}

// ---------------- K3/K4: fused prop layer: spmm gather + dense + norm ----------------
// W in 64 VGPRs/lane (register-resident: 64 distinct 16B rows per instr is
// >= 8 LDS clocks if staged in LDS -- measured 8-way conflicts, +20 us. Reverted).
// rbuf add-row broadcast stays in LDS (uniform-address ds_read_b128 = free).
// Grid 2048 = 8 blocks/CU (R7's 1024 capped occupancy at 16 waves/CU).
__global__ void __launch_bounds__(256, 4) prop_layer_kernel(
        const float* __restrict__ h_in,
        const float* __restrict__ W, const float* __restrict__ b,
        const int* __restrict__ col, const float* __restrict__ ew,
        const int* __restrict__ rp,
        float* __restrict__ out, int N, int totalWaves) {
    __shared__ float4 rbuf[4][17];
    int wid = (blockIdx.x * blockDim.x + threadIdx.x) >> 6;
    int lane = threadIdx.x & 63;
    int ws = threadIdx.x >> 6;
    int eg = lane >> 4, q = lane & 15;
    const float4* h4 = (const float4*)h_in;

    float4 Wr[16];
    const float4* W4 = (const float4*)W;
    #pragma unroll
    for (int p = 0; p < 16; ++p) Wr[p] = W4[lane * 16 + p];
    float bias = b[lane];

    for (int n = wid; n < N; n += totalWaves) {
        int s = rp[n], t = rp[n + 1];
        float4 self = h4[(size_t)n * 16 + q];
        float4 a0 = make_float4(0.f, 0.f, 0.f, 0.f);
        float4 a1 = make_float4(0.f, 0.f, 0.f, 0.f);
        int e0 = s;
        for (; e0 + 16 <= t; e0 += 16) {               // unclamped main step
            int i0 = e0 + eg, i1 = e0 + 4 + eg, i2 = e0 + 8 + eg, i3 = e0 + 12 + eg;
            int c0 = col[i0], c1 = col[i1], c2 = col[i2], c3 = col[i3];
            float w0 = ew[i0], w1 = ew[i1], w2 = ew[i2], w3 = ew[i3];
            float4 v0 = h4[(size_t)c0 * 16 + q];
            float4 v1 = h4[(size_t)c1 * 16 + q];
            float4 v2 = h4[(size_t)c2 * 16 + q];
            float4 v3 = h4[(size_t)c3 * 16 + q];
            a0.x = fmaf(w0, v0.x, a0.x); a0.y = fmaf(w0, v0.y, a0.y);
            a0.z = fmaf(w0, v0.z, a0.z); a0.w = fmaf(w0, v0.w, a0.w);
            a1.x = fmaf(w1, v1.x, a1.x); a1.y = fmaf(w1, v1.y, a1.y);
            a1.z = fmaf(w1, v1.z, a1.z); a1.w = fmaf(w1, v1.w, a1.w);
            a0.x = fmaf(w2, v2.x, a0.x); a0.y = fmaf(w2, v2.y, a0.y);
            a0.z = fmaf(w2, v2.z, a0.z); a0.w = fmaf(w2, v2.w, a0.w);
            a1.x = fmaf(w3, v3.x, a1.x); a1.y = fmaf(w3, v3.y, a1.y);
            a1.z = fmaf(w3, v3.z, a1.z); a1.w = fmaf(w3, v3.w, a1.w);
        }
        if (e0 < t) {                                  // one clamped tail step
            int j0 = e0 + eg, j1 = e0 + 4 + eg, j2 = e0 + 8 + eg, j3 = e0 + 12 + eg;
            int i0 = min(j0, t - 1), i1 = min(j1, t - 1);
            int i2 = min(j2, t - 1), i3 = min(j3, t - 1);
            int c0 = col[i0], c1 = col[i1], c2 = col[i2], c3 = col[i3];
            float w0 = (j0 < t) ? ew[i0] : 0.f;
            float w1 = (j1 < t) ? ew[i1] : 0.f;
            float w2 = (j2 < t) ? ew[i2] : 0.f;
            float w3 = (j3 < t) ? ew[i3] : 0.f;
            float4 v0 = h4[(size_t)c0 * 16 + q];
            float4 v1 = h4[(size_t)c1 * 16 + q];
            float4 v2 = h4[(size_t)c2 * 16 + q];
            float4 v3 = h4[(size_t)c3 * 16 + q];
            a0.x = fmaf(w0, v0.x, a0.x); a0.y = fmaf(w0, v0.y, a0.y);
            a0.z = fmaf(w0, v0.z, a0.z); a0.w = fmaf(w0, v0.w, a0.w);
            a1.x = fmaf(w1, v1.x, a1.x); a1.y = fmaf(w1, v1.y, a1.y);
            a1.z = fmaf(w1, v1.z, a1.z); a1.w = fmaf(w1, v1.w, a1.w);
            a0.x = fmaf(w2, v2.x, a0.x); a0.y = fmaf(w2, v2.y, a0.y);
            a0.z = fmaf(w2, v2.z, a0.z); a0.w = fmaf(w2, v2.w, a0.w);
            a1.x = fmaf(w3, v3.x, a1.x); a1.y = fmaf(w3, v3.y, a1.y);
            a1.z = fmaf(w3, v3.z, a1.z); a1.w = fmaf(w3, v3.w, a1.w);
        }
        a0.x += a1.x; a0.y += a1.y; a0.z += a1.z; a0.w += a1.w;
        // xor-butterfly over lane bits 4,5: all lanes end with the edge total
        a0.x += __shfl_xor(a0.x, 16); a0.y += __shfl_xor(a0.y, 16);
        a0.z += __shfl_xor(a0.z, 16); a0.w += __shfl_xor(a0.w, 16);
        a0.x += __shfl_xor(a0.x, 32); a0.y += __shfl_xor(a0.y, 32);
        a0.z += __shfl_xor(a0.z, 32); a0.w += __shfl_xor(a0.w, 32);

        // stage add-row to LDS (lanes 0-15 cover the 64 floats)
        if (eg == 0) {
            float4 r;
            r.x = self.x + a0.x; r.y = self.y + a0.y;
            r.z = self.z + a0.z; r.w = self.w + a0.w;
            rbuf[ws][q] = r;
        }
        asm volatile("s_waitcnt lgkmcnt(0)" ::: "memory");  // wave-synchronous

        // dense: x[lane] = relu(add . W[lane] + b[lane]), then L2-normalize
        float x0 = bias, x1 = 0.f, x2 = 0.f, x3 = 0.f;
        #pragma unroll
        for (int j = 0; j < 4; ++j) {
            float4 b0 = rbuf[ws][4 * j + 0];    // uniform addr -> broadcast
            float4 b1 = rbuf[ws][4 * j + 1];
            float4 b2 = rbuf[ws][4 * j + 2];
            float4 b3 = rbuf[ws][4 * j + 3];
            float4 w0 = Wr[4 * j + 0], w1 = Wr[4 * j + 1];
            float4 w2 = Wr[4 * j + 2], w3 = Wr[4 * j + 3];
            x0 = fmaf(b0.x, w0.x, x0); x0 = fmaf(b0.y, w0.y, x0);
            x0 = fmaf(b0.z, w0.z, x0); x0 = fmaf(b0.w, w0.w, x0);
            x1 = fmaf(b1.x, w1.x, x1); x1 = fmaf(b1.y, w1.y, x1);
            x1 = fmaf(b1.z, w1.z, x1); x1 = fmaf(b1.w, w1.w, x1);
            x2 = fmaf(b2.x, w2.x, x2); x2 = fmaf(b2.y, w2.y, x2);
            x2 = fmaf(b2.z, w2.z, x2); x2 = fmaf(b2.w, w2.w, x2);
            x3 = fmaf(b3.x, w3.x, x3); x3 = fmaf(b3.y, w3.y, x3);
            x3 = fmaf(b3.z, w3.z, x3); x3 = fmaf(b3.w, w3.w, x3);
        }
        float x = fmaxf((x0 + x1) + (x2 + x3), 0.f);

        float ss = x * x;
        #pragma unroll
        for (int off = 32; off > 0; off >>= 1) ss += __shfl_xor(ss, off);
        float scale = 1.f / fmaxf(sqrtf(ss), 1e-12f);
        out[(size_t)n * EMBED + lane] = x * scale;
    }
}

extern "C" void kernel_launch(void* const* d_in, const int* in_sizes, int n_in,
                              void* d_out, int out_size, void* d_ws, size_t ws_size,
                              hipStream_t stream) {
    const float* h0   = (const float*)d_in[0];
    const float* ha   = (const float*)d_in[1];
    const float* ta   = (const float*)d_in[2];
    const float* w1   = (const float*)d_in[3];
    const float* b1   = (const float*)d_in[4];
    const float* w2   = (const float*)d_in[5];
    const float* b2   = (const float*)d_in[6];
    const int*   erow = (const int*)d_in[7];
    const int*   ecol = (const int*)d_in[8];

    const int N = in_sizes[0] / EMBED;
    const int E = in_sizes[7];
    float* out = (float*)d_out;

    // workspace: row_ptr[N+1] ints, then edge weights[E] floats
    int*   rp = (int*)d_ws;
    size_t rp_bytes = ((size_t)(N + 1) * sizeof(int) + 255) & ~(size_t)255;
    float* ew = (float*)((char*)d_ws + rp_bytes);

    // K1: rowptr + logits (independent phases, one launch)
    rowptr_logits_kernel<<<2048, 256, 0, stream>>>(
        ha, ta, erow, ecol, rp, ew, E, N, 2048 * 256, 2048 * 4);

    // K2: out[0] = h0 copy + per-node softmax
    copy_softmax_kernel<<<2048, 256, 0, stream>>>(
        h0, out, N * EMBED / 4, rp, ew, N, 2048 * 256, 2048 * 4);

    // K3/K4: fused prop layers (grid 2048 = 8 blocks/CU, W in VGPRs)
    float* out1 = out + (size_t)N * EMBED;
    float* out2 = out + 2 * (size_t)N * EMBED;
    prop_layer_kernel<<<2048, 256, 0, stream>>>(h0,   w1, b1, ecol, ew, rp, out1, N, 2048 * 4);
    prop_layer_kernel<<<2048, 256, 0, stream>>>(out1, w2, b2, ecol, ew, rp, out2, N, 2048 * 4);
}

// Round 10
// 416.076 us; speedup vs baseline: 1.0542x; 1.0335x over previous
//
#include <hip/hip_runtime.h>
#include <math.h>

#define EMBED 64

__device__ __forceinline__ float dot4(float4 a, float4 b) {
    return fmaf(a.x, b.x, fmaf(a.y, b.y, fmaf(a.z, b.z, a.w * b.w)));
}

// reduce across the 16 lanes of an edge-subgroup (lane bits 0..3)
__device__ __forceinline__ float red16(float d) {
    d += __shfl_xor(d, 1);
    d += __shfl_xor(d, 2);
    d += __shfl_xor(d, 4);
    d += __shfl_xor(d, 8);
    return d;
}

// ---------------- K1: CSR rowptr build + edge-parallel logits (independent phases) ----------------
__global__ void __launch_bounds__(256, 8) rowptr_logits_kernel(
        const float* __restrict__ ha, const float* __restrict__ ta,
        const int* __restrict__ row, const int* __restrict__ col,
        int* __restrict__ rp, float* __restrict__ logits,
        int E, int N, int totalThreads, int totalWaves) {
    int tid = blockIdx.x * blockDim.x + threadIdx.x;

    // phase A: rowptr boundary scatter (thread per edge, grid-stride)
    for (int i = tid; i < E; i += totalThreads) {
        if (i == 0) {
            int r0 = row[0];
            for (int r = 0; r <= r0; ++r) rp[r] = 0;
        } else {
            int a = row[i - 1], b = row[i];
            for (int r = a + 1; r <= b; ++r) rp[r] = i;
        }
        if (i == E - 1) {
            int rl = row[E - 1];
            for (int r = rl + 1; r <= N; ++r) rp[r] = E;
        }
    }

    // phase B: logits, 16 edges/wave/iter = 8 row-gathers in flight
    int wid = tid >> 6;
    int lane = threadIdx.x & 63;
    int eg = lane >> 4, q = lane & 15;
    const float4* ha4 = (const float4*)ha;
    const float4* ta4 = (const float4*)ta;

    for (int base = wid * 16; base < E; base += totalWaves * 16) {
        int j0 = base + eg, j1 = base + 4 + eg, j2 = base + 8 + eg, j3 = base + 12 + eg;
        int i0 = min(j0, E - 1), i1 = min(j1, E - 1);
        int i2 = min(j2, E - 1), i3 = min(j3, E - 1);
        int r0 = row[i0], r1 = row[i1], r2 = row[i2], r3 = row[i3];
        int c0 = col[i0], c1 = col[i1], c2 = col[i2], c3 = col[i3];
        float4 t0 = ta4[(size_t)c0 * 16 + q];
        float4 t1 = ta4[(size_t)c1 * 16 + q];
        float4 t2 = ta4[(size_t)c2 * 16 + q];
        float4 t3 = ta4[(size_t)c3 * 16 + q];
        float4 a0 = ha4[(size_t)r0 * 16 + q];
        float4 a1 = ha4[(size_t)r1 * 16 + q];
        float4 a2 = ha4[(size_t)r2 * 16 + q];
        float4 a3 = ha4[(size_t)r3 * 16 + q];
        float d0 = red16(dot4(a0, t0));
        float d1 = red16(dot4(a1, t1));
        float d2 = red16(dot4(a2, t2));
        float d3 = red16(dot4(a3, t3));
        if (q == 0) {
            if (j0 < E) logits[j0] = d0;
            if (j1 < E) logits[j1] = d1;
            if (j2 < E) logits[j2] = d2;
            if (j3 < E) logits[j3] = d3;
        }
    }
}

// ---------------- K2: out[0]=h0 copy + per-node softmax (grid-stride both) ----------------
__global__ void __launch_bounds__(256) copy_softmax_kernel(
        const float* __restrict__ h0, float* __restrict__ out0, int n4,
        const int* __restrict__ rp, float* __restrict__ lw, int N,
        int totalThreads, int totalWaves) {
    int tid = blockIdx.x * blockDim.x + threadIdx.x;
    // phase A: float4 copy
    for (int i = tid; i < n4; i += totalThreads)
        ((float4*)out0)[i] = ((const float4*)h0)[i];

    // phase B: wave-per-node softmax, in-place logits -> weights
    int wid = tid >> 6;
    int lane = threadIdx.x & 63;
    for (int n = wid; n < N; n += totalWaves) {
        int s = rp[n], t = rp[n + 1];
        int deg = t - s;
        if (deg <= 0) continue;
        if (deg <= 64) {
            float v = (lane < deg) ? lw[s + lane] : -1e30f;
            float m = v;
            #pragma unroll
            for (int off = 32; off > 0; off >>= 1) m = fmaxf(m, __shfl_xor(m, off));
            float e = (lane < deg) ? __expf(v - m) : 0.f;
            float sum = e;
            #pragma unroll
            for (int off = 32; off > 0; off >>= 1) sum += __shfl_xor(sum, off);
            float inv = 1.f / fmaxf(sum, 1e-12f);
            if (lane < deg) lw[s + lane] = e * inv;
        } else {
            float m = -1e30f;
            for (int e = s + lane; e < t; e += 64) m = fmaxf(m, lw[e]);
            #pragma unroll
            for (int off = 32; off > 0; off >>= 1) m = fmaxf(m, __shfl_xor(m, off));
            float sum = 0.f;
            for (int e = s + lane; e < t; e += 64) sum += __expf(lw[e] - m);
            #pragma unroll
            for (int off = 32; off > 0; off >>= 1) sum += __shfl_xor(sum, off);
            float inv = 1.f / fmaxf(sum, 1e-12f);
            for (int e = s + lane; e < t; e += 64) lw[e] = __expf(lw[e] - m) * inv;
        }
    }
}

// ---------------- K3/K4: fused prop layer: spmm gather + dense + norm ----------------
// W in 64 VGPRs/lane (unified file: ~64 arch + 64 acc = 128/wave -> 16 waves/CU
// cap). Grid 1024 = 4 blocks/CU exactly resident -- measured optimum (grid 2048
// = two sequential batches, +9 us; W-in-LDS = 8-way conflicts, +20 us).
// rbuf add-row broadcast in LDS (uniform-address ds_read_b128 = free).
__global__ void __launch_bounds__(256, 4) prop_layer_kernel(
        const float* __restrict__ h_in,
        const float* __restrict__ W, const float* __restrict__ b,
        const int* __restrict__ col, const float* __restrict__ ew,
        const int* __restrict__ rp,
        float* __restrict__ out, int N, int totalWaves) {
    __shared__ float4 rbuf[4][17];
    int wid = (blockIdx.x * blockDim.x + threadIdx.x) >> 6;
    int lane = threadIdx.x & 63;
    int ws = threadIdx.x >> 6;
    int eg = lane >> 4, q = lane & 15;
    const float4* h4 = (const float4*)h_in;

    float4 Wr[16];
    const float4* W4 = (const float4*)W;
    #pragma unroll
    for (int p = 0; p < 16; ++p) Wr[p] = W4[lane * 16 + p];
    float bias = b[lane];

    for (int n = wid; n < N; n += totalWaves) {
        int s = rp[n], t = rp[n + 1];
        float4 self = h4[(size_t)n * 16 + q];
        float4 a0 = make_float4(0.f, 0.f, 0.f, 0.f);
        float4 a1 = make_float4(0.f, 0.f, 0.f, 0.f);
        int e0 = s;
        for (; e0 + 16 <= t; e0 += 16) {               // unclamped main step
            int i0 = e0 + eg, i1 = e0 + 4 + eg, i2 = e0 + 8 + eg, i3 = e0 + 12 + eg;
            int c0 = col[i0], c1 = col[i1], c2 = col[i2], c3 = col[i3];
            float w0 = ew[i0], w1 = ew[i1], w2 = ew[i2], w3 = ew[i3];
            float4 v0 = h4[(size_t)c0 * 16 + q];
            float4 v1 = h4[(size_t)c1 * 16 + q];
            float4 v2 = h4[(size_t)c2 * 16 + q];
            float4 v3 = h4[(size_t)c3 * 16 + q];
            a0.x = fmaf(w0, v0.x, a0.x); a0.y = fmaf(w0, v0.y, a0.y);
            a0.z = fmaf(w0, v0.z, a0.z); a0.w = fmaf(w0, v0.w, a0.w);
            a1.x = fmaf(w1, v1.x, a1.x); a1.y = fmaf(w1, v1.y, a1.y);
            a1.z = fmaf(w1, v1.z, a1.z); a1.w = fmaf(w1, v1.w, a1.w);
            a0.x = fmaf(w2, v2.x, a0.x); a0.y = fmaf(w2, v2.y, a0.y);
            a0.z = fmaf(w2, v2.z, a0.z); a0.w = fmaf(w2, v2.w, a0.w);
            a1.x = fmaf(w3, v3.x, a1.x); a1.y = fmaf(w3, v3.y, a1.y);
            a1.z = fmaf(w3, v3.z, a1.z); a1.w = fmaf(w3, v3.w, a1.w);
        }
        if (e0 < t) {                                  // one clamped tail step
            int j0 = e0 + eg, j1 = e0 + 4 + eg, j2 = e0 + 8 + eg, j3 = e0 + 12 + eg;
            int i0 = min(j0, t - 1), i1 = min(j1, t - 1);
            int i2 = min(j2, t - 1), i3 = min(j3, t - 1);
            int c0 = col[i0], c1 = col[i1], c2 = col[i2], c3 = col[i3];
            float w0 = (j0 < t) ? ew[i0] : 0.f;
            float w1 = (j1 < t) ? ew[i1] : 0.f;
            float w2 = (j2 < t) ? ew[i2] : 0.f;
            float w3 = (j3 < t) ? ew[i3] : 0.f;
            float4 v0 = h4[(size_t)c0 * 16 + q];
            float4 v1 = h4[(size_t)c1 * 16 + q];
            float4 v2 = h4[(size_t)c2 * 16 + q];
            float4 v3 = h4[(size_t)c3 * 16 + q];
            a0.x = fmaf(w0, v0.x, a0.x); a0.y = fmaf(w0, v0.y, a0.y);
            a0.z = fmaf(w0, v0.z, a0.z); a0.w = fmaf(w0, v0.w, a0.w);
            a1.x = fmaf(w1, v1.x, a1.x); a1.y = fmaf(w1, v1.y, a1.y);
            a1.z = fmaf(w1, v1.z, a1.z); a1.w = fmaf(w1, v1.w, a1.w);
            a0.x = fmaf(w2, v2.x, a0.x); a0.y = fmaf(w2, v2.y, a0.y);
            a0.z = fmaf(w2, v2.z, a0.z); a0.w = fmaf(w2, v2.w, a0.w);
            a1.x = fmaf(w3, v3.x, a1.x); a1.y = fmaf(w3, v3.y, a1.y);
            a1.z = fmaf(w3, v3.z, a1.z); a1.w = fmaf(w3, v3.w, a1.w);
        }
        a0.x += a1.x; a0.y += a1.y; a0.z += a1.z; a0.w += a1.w;
        // xor-butterfly over lane bits 4,5: all lanes end with the edge total
        a0.x += __shfl_xor(a0.x, 16); a0.y += __shfl_xor(a0.y, 16);
        a0.z += __shfl_xor(a0.z, 16); a0.w += __shfl_xor(a0.w, 16);
        a0.x += __shfl_xor(a0.x, 32); a0.y += __shfl_xor(a0.y, 32);
        a0.z += __shfl_xor(a0.z, 32); a0.w += __shfl_xor(a0.w, 32);

        // stage add-row to LDS (lanes 0-15 cover the 64 floats)
        if (eg == 0) {
            float4 r;
            r.x = self.x + a0.x; r.y = self.y + a0.y;
            r.z = self.z + a0.z; r.w = self.w + a0.w;
            rbuf[ws][q] = r;
        }
        asm volatile("s_waitcnt lgkmcnt(0)" ::: "memory");  // wave-synchronous

        // dense: x[lane] = relu(add . W[lane] + b[lane]), then L2-normalize
        float x0 = bias, x1 = 0.f, x2 = 0.f, x3 = 0.f;
        #pragma unroll
        for (int j = 0; j < 4; ++j) {
            float4 b0 = rbuf[ws][4 * j + 0];    // uniform addr -> broadcast
            float4 b1 = rbuf[ws][4 * j + 1];
            float4 b2 = rbuf[ws][4 * j + 2];
            float4 b3 = rbuf[ws][4 * j + 3];
            float4 w0 = Wr[4 * j + 0], w1 = Wr[4 * j + 1];
            float4 w2 = Wr[4 * j + 2], w3 = Wr[4 * j + 3];
            x0 = fmaf(b0.x, w0.x, x0); x0 = fmaf(b0.y, w0.y, x0);
            x0 = fmaf(b0.z, w0.z, x0); x0 = fmaf(b0.w, w0.w, x0);
            x1 = fmaf(b1.x, w1.x, x1); x1 = fmaf(b1.y, w1.y, x1);
            x1 = fmaf(b1.z, w1.z, x1); x1 = fmaf(b1.w, w1.w, x1);
            x2 = fmaf(b2.x, w2.x, x2); x2 = fmaf(b2.y, w2.y, x2);
            x2 = fmaf(b2.z, w2.z, x2); x2 = fmaf(b2.w, w2.w, x2);
            x3 = fmaf(b3.x, w3.x, x3); x3 = fmaf(b3.y, w3.y, x3);
            x3 = fmaf(b3.z, w3.z, x3); x3 = fmaf(b3.w, w3.w, x3);
        }
        float x = fmaxf((x0 + x1) + (x2 + x3), 0.f);

        float ss = x * x;
        #pragma unroll
        for (int off = 32; off > 0; off >>= 1) ss += __shfl_xor(ss, off);
        float scale = 1.f / fmaxf(sqrtf(ss), 1e-12f);
        out[(size_t)n * EMBED + lane] = x * scale;
    }
}

extern "C" void kernel_launch(void* const* d_in, const int* in_sizes, int n_in,
                              void* d_out, int out_size, void* d_ws, size_t ws_size,
                              hipStream_t stream) {
    const float* h0   = (const float*)d_in[0];
    const float* ha   = (const float*)d_in[1];
    const float* ta   = (const float*)d_in[2];
    const float* w1   = (const float*)d_in[3];
    const float* b1   = (const float*)d_in[4];
    const float* w2   = (const float*)d_in[5];
    const float* b2   = (const float*)d_in[6];
    const int*   erow = (const int*)d_in[7];
    const int*   ecol = (const int*)d_in[8];

    const int N = in_sizes[0] / EMBED;
    const int E = in_sizes[7];
    float* out = (float*)d_out;

    // workspace: row_ptr[N+1] ints, then edge weights[E] floats
    int*   rp = (int*)d_ws;
    size_t rp_bytes = ((size_t)(N + 1) * sizeof(int) + 255) & ~(size_t)255;
    float* ew = (float*)((char*)d_ws + rp_bytes);

    // K1: rowptr + logits (independent phases, one launch)
    rowptr_logits_kernel<<<2048, 256, 0, stream>>>(
        ha, ta, erow, ecol, rp, ew, E, N, 2048 * 256, 2048 * 4);

    // K2: out[0] = h0 copy + per-node softmax
    copy_softmax_kernel<<<2048, 256, 0, stream>>>(
        h0, out, N * EMBED / 4, rp, ew, N, 2048 * 256, 2048 * 4);

    // K3/K4: fused prop layers (grid 1024 = 4 blocks/CU exactly resident)
    float* out1 = out + (size_t)N * EMBED;
    float* out2 = out + 2 * (size_t)N * EMBED;
    prop_layer_kernel<<<1024, 256, 0, stream>>>(h0,   w1, b1, ecol, ew, rp, out1, N, 1024 * 4);
    prop_layer_kernel<<<1024, 256, 0, stream>>>(out1, w2, b2, ecol, ew, rp, out2, N, 1024 * 4);
}